// Round 1
// 382.940 us; speedup vs baseline: 1.0075x; 1.0075x over previous
//
#include <hip/hip_runtime.h>

// EGAttention: B=4,H=128,W=128,C=256,NH=8,HD=32. 512 windows x 8 heads.
// v2: latency-bound fix. LDS 44KB->19KB (4 blocks/CU), analytic rank-2 bias
// (no gd LUT / no per-element LDS gather), cvt_pk bf16 conversions, per-wave
// P chunk buffer (lazy P from acc regs) -> single barrier, per-wave atomics.

typedef __attribute__((ext_vector_type(8))) short bf16x8;
typedef __attribute__((ext_vector_type(4))) float f32x4;

#define PI_F 3.14159265358979323846f
#define THETA (PI_F / 127.0f)   // linspace(0,128,128) step * 2pi/128 halved: sin((j-i)*pi/127)

__device__ __forceinline__ unsigned cvt_pk_bf16(float lo, float hi) {
    unsigned r;
    asm("v_cvt_pk_bf16_f32 %0, %1, %2" : "=v"(r) : "v"(lo), "v"(hi));
    return r;
}

__device__ __forceinline__ bf16x8 load_frag8(const float* __restrict__ p) {
    float4 x0 = *(const float4*)p;
    float4 x1 = *(const float4*)(p + 4);
    union { unsigned u[4]; bf16x8 v; } r;
    r.u[0] = cvt_pk_bf16(x0.x, x0.y);
    r.u[1] = cvt_pk_bf16(x0.z, x0.w);
    r.u[2] = cvt_pk_bf16(x1.x, x1.y);
    r.u[3] = cvt_pk_bf16(x1.z, x1.w);
    return r.v;
}

__global__ __launch_bounds__(256, 4) void eg_attn_main(
    const float* __restrict__ q, const float* __restrict__ k,
    const float* __restrict__ v, float* __restrict__ out,
    float* __restrict__ wsum)
{
    const int bx = blockIdx.x;
    const int w = bx >> 3;          // window (0..511)
    const int n = bx & 7;           // head
    const int t = threadIdx.x;
    const int lane = t & 63, wv = t >> 6;
    const int quad = lane >> 4, l15 = lane & 15;

    __shared__ __align__(16) short vtbuf[32 * 136];     // V^T bf16 [d][j], 8.5 KB
    __shared__ __align__(16) short pchunk[4 * 32 * 40]; // per-wave P chunk [32 rows][32+8 pad], 10 KB

    // ---- stage V^T (bf16) into LDS: thread t -> row j=t&127, d-range (t>>7)*16..+15 ----
    {
        const int j = t & 127, dq = t >> 7;
        const float* vp = v + (size_t)(w * 128 + j) * 256 + n * 32 + dq * 16;
        float4 a0 = ((const float4*)vp)[0];
        float4 a1 = ((const float4*)vp)[1];
        float4 a2 = ((const float4*)vp)[2];
        float4 a3 = ((const float4*)vp)[3];
        float tmp[16] = {a0.x, a0.y, a0.z, a0.w, a1.x, a1.y, a1.z, a1.w,
                         a2.x, a2.y, a2.z, a2.w, a3.x, a3.y, a3.z, a3.w};
#pragma unroll
        for (int m = 0; m < 8; m++) {
            unsigned u = cvt_pk_bf16(tmp[2 * m], tmp[2 * m + 1]);
            vtbuf[(dq * 16 + 2 * m) * 136 + j]     = (short)u;
            vtbuf[(dq * 16 + 2 * m + 1) * 136 + j] = (short)(u >> 16);
        }
    }

    // ---- QK^T: wave wv owns rows m0..m0+31, all 128 cols. K=32 = one MFMA. ----
    const int m0 = wv * 32;
    const float* qb = q + (size_t)(w * 128) * 256 + n * 32;
    const float* kb = k + (size_t)(w * 128) * 256 + n * 32;

    bf16x8 aq[2], bk[8];
#pragma unroll
    for (int ti = 0; ti < 2; ti++)
        aq[ti] = load_frag8(qb + (m0 + ti * 16 + l15) * 256 + quad * 8);
#pragma unroll
    for (int tj = 0; tj < 8; tj++)
        bk[tj] = load_frag8(kb + (tj * 16 + l15) * 256 + quad * 8);

    f32x4 acc[2][8];
#pragma unroll
    for (int ti = 0; ti < 2; ti++)
#pragma unroll
        for (int tj = 0; tj < 8; tj++) {
            f32x4 z = {0.f, 0.f, 0.f, 0.f};
            acc[ti][tj] = z;
        }
#pragma unroll
    for (int ti = 0; ti < 2; ti++)
#pragma unroll
        for (int tj = 0; tj < 8; tj++)
            acc[ti][tj] = __builtin_amdgcn_mfma_f32_16x16x32_bf16(
                aq[ti], bk[tj], acc[ti][tj], 0, 0, 0);

    // ---- analytic bias: bias(i,j) = 2*cb*sin((j-i)*theta)
    //      = (2cb*sin(j*th))*cos(i*th) - (2cb*cos(j*th))*sin(i*th). Pure register phase.
    const float cb2 = 0.2f * __sinf((float)(w & 127) * (PI_F / 128.0f));
    float sjs[8], cjs[8];
#pragma unroll
    for (int tj = 0; tj < 8; tj++) {
        float aj = (float)(tj * 16 + l15) * THETA;    // j = tj*16 + l15
        sjs[tj] = cb2 * __sinf(aj);
        cjs[tj] = cb2 * __cosf(aj);
    }

    float rsv[2][4];
    float lsum = 0.f;
#pragma unroll
    for (int ti = 0; ti < 2; ti++) {
#pragma unroll
        for (int r = 0; r < 4; r++) {
            const int i = m0 + ti * 16 + quad * 4 + r;   // C-layout row
            const float ai = (float)i * THETA;
            const float si = __sinf(ai), ci = __cosf(ai);
            float ss = 0.f;
#pragma unroll
            for (int tj = 0; tj < 8; tj++) {
                float val = fmaf(sjs[tj], ci, fmaf(-cjs[tj], si, acc[ti][tj][r]));
                acc[ti][tj][r] = val;                    // keep biased S in regs
                ss += val * val;
                lsum += fabsf(val);
            }
            // row sum-of-squares across the 16 lanes of this quad
            ss += __shfl_xor(ss, 1);
            ss += __shfl_xor(ss, 2);
            ss += __shfl_xor(ss, 4);
            ss += __shfl_xor(ss, 8);
            rsv[ti][r] = 1.57079632679f / fmaxf(sqrtf(ss), 1e-12f);
        }
    }

    // per-window |attn| sum -> one atomic per wave (no 2nd barrier needed)
#pragma unroll
    for (int mask = 1; mask < 64; mask <<= 1) lsum += __shfl_xor(lsum, mask);
    if (lane == 0) atomicAdd(wsum + w, lsum);

    __syncthreads();   // vtbuf staged by all threads; hidden under the attn phase above

    // ---- x_u = P @ V, K=j in 4 chunks of 32; P computed lazily per chunk into
    //      a per-wave LDS buffer (same-wave DS ops are in-order; no barriers). ----
    short* pw = pchunk + wv * (32 * 40);
    f32x4 xacc[2][2];
#pragma unroll
    for (int ti = 0; ti < 2; ti++)
#pragma unroll
        for (int tn = 0; tn < 2; tn++) {
            f32x4 z = {0.f, 0.f, 0.f, 0.f};
            xacc[ti][tn] = z;
        }

#pragma unroll
    for (int kk = 0; kk < 4; kk++) {
        // V frags for this K-chunk (B-operand): lane holds V[j=kk*32+quad*8+e][d=tn*16+l15]
        bf16x8 v0 = *(const bf16x8*)&vtbuf[(l15) * 136 + kk * 32 + quad * 8];
        bf16x8 v1 = *(const bf16x8*)&vtbuf[(16 + l15) * 136 + kk * 32 + quad * 8];

        // P chunk: cols j = kk*32..+31 = tiles tj=2kk (col l15) and 2kk+1 (col 16+l15)
#pragma unroll
        for (int ti = 0; ti < 2; ti++)
#pragma unroll
            for (int r = 0; r < 4; r++) {
                const float rs = rsv[ti][r];
                float p0 = 1.0f - __cosf(acc[ti][2 * kk][r] * rs);
                float p1 = 1.0f - __cosf(acc[ti][2 * kk + 1][r] * rs);
                unsigned u = cvt_pk_bf16(p0, p1);
                const int row = ti * 16 + quad * 4 + r;
                pw[row * 40 + l15]      = (short)u;
                pw[row * 40 + 16 + l15] = (short)(u >> 16);
            }

        // A-frags: lane holds P[i=m0+ti*16+l15][j=kk*32+quad*8+e] (80B row stride, 16B aligned)
        bf16x8 pa0 = *(const bf16x8*)&pw[(l15) * 40 + quad * 8];
        bf16x8 pa1 = *(const bf16x8*)&pw[(16 + l15) * 40 + quad * 8];

        xacc[0][0] = __builtin_amdgcn_mfma_f32_16x16x32_bf16(pa0, v0, xacc[0][0], 0, 0, 0);
        xacc[0][1] = __builtin_amdgcn_mfma_f32_16x16x32_bf16(pa0, v1, xacc[0][1], 0, 0, 0);
        xacc[1][0] = __builtin_amdgcn_mfma_f32_16x16x32_bf16(pa1, v0, xacc[1][0], 0, 0, 0);
        xacc[1][1] = __builtin_amdgcn_mfma_f32_16x16x32_bf16(pa1, v1, xacc[1][1], 0, 0, 0);
    }

    // store ungated x_u
    float* ob = out + (size_t)(w * 128) * 256 + n * 32;
#pragma unroll
    for (int ti = 0; ti < 2; ti++)
#pragma unroll
        for (int tn = 0; tn < 2; tn++)
#pragma unroll
            for (int r = 0; r < 4; r++) {
                const int i = m0 + ti * 16 + quad * 4 + r;
                ob[i * 256 + tn * 16 + l15] = xacc[ti][tn][r];
            }
}

// 512 window sums -> M_w = max(s/smax, 0.5)
__global__ __launch_bounds__(512) void eg_gate(const float* __restrict__ wsum,
                                               float* __restrict__ M)
{
    const int t = threadIdx.x;   // 512 threads
    __shared__ float red[8];
    const float s = wsum[t];
    float m = s;
#pragma unroll
    for (int mask = 1; mask < 64; mask <<= 1) m = fmaxf(m, __shfl_xor(m, mask));
    if ((t & 63) == 0) red[t >> 6] = m;
    __syncthreads();
    if (t == 0) {
        float mm = red[0];
#pragma unroll
        for (int i = 1; i < 8; i++) mm = fmaxf(mm, red[i]);
        red[0] = mm;
    }
    __syncthreads();
    M[t] = fmaxf(s / red[0], 0.5f);
}

// out = x_u * M + res * (1 - M)
__global__ __launch_bounds__(256) void eg_finalize(float* __restrict__ out,
                                                   const float* __restrict__ res,
                                                   const float* __restrict__ M)
{
    const int tid = blockIdx.x * 256 + threadIdx.x;   // 4194304 float4s
    const float Mw = M[tid >> 13];                    // window = (tid*4)>>15
    const float om = 1.0f - Mw;
    float4 x = ((const float4*)out)[tid];
    float4 r = ((const float4*)res)[tid];
    x.x = x.x * Mw + r.x * om;
    x.y = x.y * Mw + r.y * om;
    x.z = x.z * Mw + r.z * om;
    x.w = x.w * Mw + r.w * om;
    ((float4*)out)[tid] = x;
}

extern "C" void kernel_launch(void* const* d_in, const int* in_sizes, int n_in,
                              void* d_out, int out_size, void* d_ws, size_t ws_size,
                              hipStream_t stream) {
    const float* qkv = (const float*)d_in[0];
    const float* res = (const float*)d_in[1];
    const long plane = 16777216L;               // B*HW*C
    const float* q = qkv;
    const float* k = qkv + plane;
    const float* v = qkv + 2 * plane;
    float* out = (float*)d_out;

    float* wsum = (float*)d_ws;                 // 512 floats
    float* M = wsum + 512;                      // 512 floats

    hipMemsetAsync(wsum, 0, 512 * sizeof(float), stream);
    eg_attn_main<<<4096, 256, 0, stream>>>(q, k, v, out, wsum);
    eg_gate<<<1, 512, 0, stream>>>(wsum, M);
    eg_finalize<<<16384, 256, 0, stream>>>(out, res, M);
}